// Round 6
// baseline (165.590 us; speedup 1.0000x reference)
//
#include <hip/hip_runtime.h>
#include <math.h>

// B,H,W,C = 4,384,384,48; KERNEL=3 -> 128x128 output, 48 "channels" g.
// Output F=((b*128+r)*128+cc)*48+g consumes 9 contiguous floats at input row
// (b*384+3r+kr), float offset cc*144+(g&15)*9, kr=g>>4.
// Block = (b, r, kr, quarter c4): stages 4608 contiguous floats (32 cc values
// x 144), computes 32cc x 16g = 512 outputs with 256 threads, 2 outputs per
// thread (cc pair) in packed-f32 (v_pk_*) arithmetic.
#define EPS 1e-4f

typedef float f2 __attribute__((ext_vector_type(2)));

static __device__ __forceinline__ float rcp_f(float a) {
    return __builtin_amdgcn_rcpf(a);                 // v_rcp_f32, 1 ulp
}
static __device__ __forceinline__ f2 sp(float a) { f2 r; r.x = a; r.y = a; return r; }
static __device__ __forceinline__ f2 exp2_2(f2 a) {
    f2 r; r.x = __builtin_amdgcn_exp2f(a.x); r.y = __builtin_amdgcn_exp2f(a.y); return r;
}
static __device__ __forceinline__ f2 rcp_2(f2 a) { f2 r; r.x = rcp_f(a.x); r.y = rcp_f(a.y); return r; }
static __device__ __forceinline__ f2 max2(f2 a, f2 b) { return __builtin_elementwise_max(a, b); }
static __device__ __forceinline__ f2 min2(f2 a, f2 b) { return __builtin_elementwise_min(a, b); }
static __device__ __forceinline__ f2 abs2(f2 a) { return __builtin_elementwise_max(a, -a); } // finite inputs

__global__ __launch_bounds__(256, 4)   // min 4 waves/EU -> VGPR cap 128
void fuzzy_pool_kernel(const float* __restrict__ x, float* __restrict__ out) {
    __shared__ float s[4608];          // 18432 B staged input (one kr-row quarter)

    const int tid = threadIdx.x;
    const int bid = blockIdx.x;        // ((b*128+r)*3 + kr)*4 + c4
    const int c4 = bid & 3;
    const int t1 = bid >> 2;
    const int kr = t1 % 3;             // scalar magic-mul
    const int t2 = t1 / 3;
    const int r  = t2 & 127;
    const int b  = t2 >> 7;

    const float* __restrict__ src =
        x + ((size_t)(b * 384 + 3 * r + kr) * 18432 + c4 * 4608);

    // ---- coalesced global -> LDS staging: 1152 float4, 16B/lane ----
    const float4* __restrict__ g4 = (const float4*)src;
    float4* l4 = (float4*)s;
#pragma unroll
    for (int k = 0; k < 4; ++k) l4[tid + 256 * k] = g4[tid + 256 * k];
    if (tid < 128) l4[tid + 1024] = g4[tid + 1024];
    __syncthreads();

    // thread (ip = cc-pair 0..15, j = g' 0..15); halves: cc=2ip (+0), cc=2ip+1 (+144)
    const int ip = tid >> 4;
    const int j  = tid & 15;
    const int base = ip * 288 + j * 9;

    f2 v[9];
#pragma unroll
    for (int t = 0; t < 9; ++t) {      // ds_read2-able pairs; 4-way banks (cheap)
        f2 tv; tv.x = s[base + t]; tv.y = s[base + 144 + t]; v[t] = tv;
    }

    const float R3 = 1.0f/3.0f, R5 = 0.2f, R7 = 1.0f/7.0f, R9 = 1.0f/9.0f;
    const float NC = -0.5f * 1.44269504088896340736f;   // -0.5*log2(e)

    // ---- membership(x): nested sums (packed) ----
    const f2 s3 = v[3] + v[4] + v[5];
    const f2 s5 = s3 + v[2] + v[6];
    const f2 s7 = s5 + v[1] + v[7];
    const f2 s9 = s7 + v[0] + v[8];
    const f2 m3 = s3 * R3, m5 = s5 * R5, m7 = s7 * R7, m9 = s9 * R9;

    f2 kmm[5];
    kmm[0] = m7; kmm[1] = m5; kmm[2] = m3; kmm[3] = v[4]; kmm[4] = m9;

    const f2 v_avg = (m7 + m5 + m3 + v[4] + m9) * R5;

    // ---- omega = |x - v_avg|; var = membership(omega) + eps ----
    f2 w[9];
#pragma unroll
    for (int t = 0; t < 9; ++t) w[t] = abs2(v[t] - v_avg);

    const f2 t3 = w[3] + w[4] + w[5];
    const f2 t5 = t3 + w[2] + w[6];
    const f2 t7 = t5 + w[1] + w[7];
    const f2 t9 = t7 + w[0] + w[8];
    const f2 var4 = t9 * R9 + sp(EPS);       // var[...,4] (m_only_var probe)

    f2 c[5];                                  // c_j = -0.5*log2e / var_j
    c[0] = NC * rcp_2(t7 * R7 + sp(EPS));
    c[1] = NC * rcp_2(t5 * R5 + sp(EPS));
    c[2] = NC * rcp_2(t3 * R3 + sp(EPS));
    c[3] = NC * rcp_2(w[4] + sp(EPS));
    c[4] = NC * rcp_2(var4);

    // ---- pi[jj][t] = 2^(c_jj d^2); sum over jj (all t), max over jj (t!=4) ----
    // Exact: pi[3][4] = 1.0 bit-exactly (d = v4-v4 = +-0); all pi <= 1 so
    // max_pi[4] = 1.0 and t=4 drops out of the thresh min-tree.
    f2 sum_pi[9], max_pi[9];
#pragma unroll
    for (int t = 0; t < 9; ++t) { sum_pi[t] = sp(0.f); max_pi[t] = sp(0.f); }

#pragma unroll
    for (int jj = 0; jj < 5; ++jj) {
        const f2 k  = kmm[jj];
        const f2 cj = c[jj];
#pragma unroll
        for (int t = 0; t < 9; ++t) {
            if (jj == 3 && t == 4) {          // same summation slot/order
                sum_pi[4] += sp(1.0f);
                continue;
            }
            const f2 d  = v[t] - k;
            const f2 pi = exp2_2(cj * d * d); // v_exp_f32 x2
            sum_pi[t] += pi;
            if (t != 4) max_pi[t] = max2(max_pi[t], pi);
        }
    }

    f2 thresh = min2(min2(max_pi[0], max_pi[1]), max_pi[2]);
    thresh = min2(thresh, max_pi[3]);
    thresh = min2(min2(thresh, max_pi[5]), max_pi[6]);
    thresh = min2(min2(thresh, max_pi[7]), max_pi[8]);

    // any_t(sum*0.2 > thresh) <=> max_t(sum)*0.2 > thresh (monotone rounding)
    f2 ms = max2(max2(sum_pi[0], sum_pi[1]), sum_pi[2]);
    ms = max2(max2(ms, sum_pi[3]), sum_pi[4]);
    ms = max2(max2(ms, sum_pi[5]), sum_pi[6]);
    ms = max2(max2(ms, sum_pi[7]), sum_pi[8]);

    // weighted-average denoising; 0.2 cancels in the ratio
    f2 sn = sp(0.f), sd = sp(0.f);
#pragma unroll
    for (int t = 0; t < 9; ++t) { sn += sum_pi[t] * v[t]; sd += sum_pi[t]; }
    const f2 denoised = sn * rcp_2(sd);

    const float resx = (ms.x * R5 > thresh.x) ? m9.x
                       : ((var4.x < EPS) ? v_avg.x : denoised.x);
    const float resy = (ms.y * R5 > thresh.y) ? m9.y
                       : ((var4.y < EPS) ? v_avg.y : denoised.y);

    const int cc0 = c4 * 32 + 2 * ip;
    const int g   = kr * 16 + j;
    const size_t ob = ((size_t)((b * 128 + r) * 128 + cc0)) * 48 + g;
    out[ob]      = resx;
    out[ob + 48] = resy;
}

extern "C" void kernel_launch(void* const* d_in, const int* in_sizes, int n_in,
                              void* d_out, int out_size, void* d_ws, size_t ws_size,
                              hipStream_t stream) {
    (void)in_sizes; (void)n_in; (void)d_ws; (void)ws_size; (void)out_size;
    const float* x = (const float*)d_in[0];
    float* out = (float*)d_out;
    const int blocks = 4 * 128 * 3 * 4;   // (b, r, kr, c4) = 6144
    fuzzy_pool_kernel<<<blocks, 256, 0, stream>>>(x, out);
}